// Round 1
// baseline (199.110 us; speedup 1.0000x reference)
//
#include <hip/hip_runtime.h>

// PPO model loss: GAE (reverse affine scan) + whitening stats + clipped losses.
// Inputs (fp32, B=1024 x T=4096): logprobs, values, old_logprobs, old_values,
// rewards, mask(int32). Output: scalar fp32 loss.
//
// ws layout (doubles): [0]=sum(adv) [1]=sum(adv^2) [2]=vf_sum [3]=pg_sum [4]=n

static constexpr int T_DIM = 4096;
static constexpr int BT    = 256;          // threads per block (one row/block)
static constexpr int CH    = T_DIM / BT;   // 16 elements per thread
static constexpr int NW    = BT / 64;      // 4 waves per block

#define CDEC 0.95f          // gamma * lam
#define CLIPR 0.2f
#define CLIPV 0.2f

__device__ __forceinline__ double wave_sum_d(double v) {
#pragma unroll
  for (int d = 32; d > 0; d >>= 1) v += __shfl_down(v, d);
  return v;
}

// ---------------- Kernel 1: GAE scan + whitening stats (single pass) --------
__global__ __launch_bounds__(BT) void gae_stats_kernel(
    const float* __restrict__ old_values,
    const float* __restrict__ rewards,
    double* __restrict__ acc) {
  const int row  = blockIdx.x;
  const int tid  = threadIdx.x;
  const int lane = tid & 63;
  const int wave = tid >> 6;
  const float c  = CDEC;
  const long base = (long)row * T_DIM + tid * CH;

  // per-chunk power sums: Qc = sum_{i=1..CH} c^i, Q2 = sum c^{2i}, M = c^CH
  float Qc = 0.f, Q2 = 0.f, M;
  {
    float pw = 1.f;
#pragma unroll
    for (int i = 0; i < CH; ++i) { pw *= c; Qc += pw; Q2 += pw * pw; }
    M = pw;
  }

  // next old_value beyond this chunk (0 past end of row)
  float nv = (tid == BT - 1) ? 0.f : old_values[base + CH];

  // pass over chunk, high t -> low t. L = local suffix scan value.
  float L = 0.f, P = 0.f, P2 = 0.f, cross = 0.f, pw = 1.f;
#pragma unroll
  for (int jj = CH - 4; jj >= 0; jj -= 4) {
    const float4 rv = *(const float4*)(rewards + base + jj);
    const float4 vv = *(const float4*)(old_values + base + jj);
    float d;
    d = rv.w + nv - vv.w; L = d + c * L; pw *= c; P += L; P2 += L * L; cross += L * pw; nv = vv.w;
    d = rv.z + nv - vv.z; L = d + c * L; pw *= c; P += L; P2 += L * L; cross += L * pw; nv = vv.z;
    d = rv.y + nv - vv.y; L = d + c * L; pw *= c; P += L; P2 += L * L; cross += L * pw; nv = vv.y;
    d = rv.x + nv - vv.x; L = d + c * L; pw *= c; P += L; P2 += L * L; cross += L * pw; nv = vv.x;
  }

  // inclusive suffix scan of affine (L, M) across the wave (lane k covers k..63)
  float sL = L, sM = M;
#pragma unroll
  for (int d = 1; d < 64; d <<= 1) {
    float oL = __shfl_down(sL, d);
    float oM = __shfl_down(sM, d);
    if (lane + d < 64) { sL += sM * oL; sM *= oM; }
  }

  __shared__ float wL[NW], wM[NW];
  if (lane == 0) { wL[wave] = sL; wM[wave] = sM; }
  __syncthreads();

  // carry into this wave = composition of later waves applied to 0
  float Sw = 0.f;
  for (int w = NW - 1; w > wave; --w) Sw = wL[w] + wM[w] * Sw;

  // carry into this thread = suffix of lanes (lane+1..63) applied to Sw
  float nL = __shfl_down(sL, 1);
  float nM = __shfl_down(sM, 1);
  if (lane == 63) { nL = 0.f; nM = 1.f; }
  const float carry = nL + nM * Sw;

  // closed-form chunk stats: sum(adv) and sum(adv^2)
  const float s1 = P + Qc * carry;
  const float s2 = P2 + 2.f * carry * cross + Q2 * carry * carry;

  __shared__ double red[2][NW];
  double r1 = wave_sum_d((double)s1);
  double r2 = wave_sum_d((double)s2);
  if (lane == 0) { red[0][wave] = r1; red[1][wave] = r2; }
  __syncthreads();
  if (tid == 0) {
    double t1 = 0.0, t2 = 0.0;
    for (int w = 0; w < NW; ++w) { t1 += red[0][w]; t2 += red[1][w]; }
    atomicAdd(&acc[0], t1);
    atomicAdd(&acc[1], t2);
  }
}

// ---------------- Kernel 2: regenerate adv + losses ------------------------
__global__ __launch_bounds__(BT) void loss_kernel(
    const float* __restrict__ logprobs,
    const float* __restrict__ values,
    const float* __restrict__ old_logprobs,
    const float* __restrict__ old_values,
    const float* __restrict__ rewards,
    const int*   __restrict__ mask,
    double* __restrict__ acc,
    long Ntot) {
  const int row  = blockIdx.x;
  const int tid  = threadIdx.x;
  const int lane = tid & 63;
  const int wave = tid >> 6;
  const float c  = CDEC;
  const long base = (long)row * T_DIM + tid * CH;

  // whitening constants from kernel-1 stats
  const double S1 = acc[0], S2 = acc[1];
  const double mean_d = S1 / (double)Ntot;
  const double var_d  = (S2 - S1 * S1 / (double)Ntot) / (double)(Ntot - 1);
  const float meanf   = (float)mean_d;
  const float invstdf = (float)(1.0 / sqrt(var_d + 1e-8));

  float M;
  {
    float pw = 1.f;
#pragma unroll
    for (int i = 0; i < CH; ++i) pw *= c;
    M = pw;
  }

  float nv0 = (tid == BT - 1) ? 0.f : old_values[base + CH];

  // pass 1: chunk affine (L, M)
  float L = 0.f;
  {
    float nv = nv0;
#pragma unroll
    for (int jj = CH - 4; jj >= 0; jj -= 4) {
      const float4 rv = *(const float4*)(rewards + base + jj);
      const float4 vv = *(const float4*)(old_values + base + jj);
      float d;
      d = rv.w + nv - vv.w; L = d + c * L; nv = vv.w;
      d = rv.z + nv - vv.z; L = d + c * L; nv = vv.z;
      d = rv.y + nv - vv.y; L = d + c * L; nv = vv.y;
      d = rv.x + nv - vv.x; L = d + c * L; nv = vv.x;
    }
  }

  float sL = L, sM = M;
#pragma unroll
  for (int d = 1; d < 64; d <<= 1) {
    float oL = __shfl_down(sL, d);
    float oM = __shfl_down(sM, d);
    if (lane + d < 64) { sL += sM * oL; sM *= oM; }
  }

  __shared__ float wL[NW], wM[NW];
  if (lane == 0) { wL[wave] = sL; wM[wave] = sM; }
  __syncthreads();

  float Sw = 0.f;
  for (int w = NW - 1; w > wave; --w) Sw = wL[w] + wM[w] * Sw;

  float nL = __shfl_down(sL, 1);
  float nM = __shfl_down(sM, 1);
  if (lane == 63) { nL = 0.f; nM = 1.f; }
  const float carry = nL + nM * Sw;

  // pass 2: regenerate adv, compute losses
  float A = carry;
  float vf_s = 0.f, pg_s = 0.f, n_s = 0.f;
  {
    float nv = nv0;
#pragma unroll
    for (int jj = CH - 4; jj >= 0; jj -= 4) {
      const float4 rv = *(const float4*)(rewards + base + jj);
      const float4 vv = *(const float4*)(old_values + base + jj);
      const float4 va = *(const float4*)(values + base + jj);
      const float4 lp = *(const float4*)(logprobs + base + jj);
      const float4 ol = *(const float4*)(old_logprobs + base + jj);
      const int4  mk  = *(const int4*)(mask + base + jj);
#define STEP(RC, VC, AC, LC, OC, MC)                                           \
      {                                                                        \
        const float d = RC + nv - VC;                                          \
        A = d + c * A;                                                         \
        const float mf = (float)MC;                                            \
        const float ret = A + VC;                                              \
        const float vc2 = fminf(fmaxf(AC, VC - CLIPV), VC + CLIPV);            \
        const float d1 = AC - ret, d2 = vc2 - ret;                             \
        vf_s += fmaxf(d1 * d1, d2 * d2) * mf;                                  \
        const float lr = (LC - OC) * mf;                                       \
        const float ratio = expf(lr);                                          \
        const float a = (A - meanf) * invstdf;                                 \
        const float p1 = -a * ratio;                                           \
        const float p2 = -a * fminf(fmaxf(ratio, 1.f - CLIPR), 1.f + CLIPR);   \
        pg_s += fmaxf(p1, p2) * mf;                                            \
        n_s += mf;                                                             \
        nv = VC;                                                               \
      }
      STEP(rv.w, vv.w, va.w, lp.w, ol.w, mk.w)
      STEP(rv.z, vv.z, va.z, lp.z, ol.z, mk.z)
      STEP(rv.y, vv.y, va.y, lp.y, ol.y, mk.y)
      STEP(rv.x, vv.x, va.x, lp.x, ol.x, mk.x)
#undef STEP
    }
  }

  __shared__ double red[3][NW];
  double rv0 = wave_sum_d((double)vf_s);
  double rv1 = wave_sum_d((double)pg_s);
  double rv2 = wave_sum_d((double)n_s);
  if (lane == 0) { red[0][wave] = rv0; red[1][wave] = rv1; red[2][wave] = rv2; }
  __syncthreads();
  if (tid == 0) {
    double t0 = 0.0, t1 = 0.0, t2 = 0.0;
    for (int w = 0; w < NW; ++w) { t0 += red[0][w]; t1 += red[1][w]; t2 += red[2][w]; }
    atomicAdd(&acc[2], t0);
    atomicAdd(&acc[3], t1);
    atomicAdd(&acc[4], t2);
  }
}

// ---------------- Kernel 3: finalize ---------------------------------------
__global__ void finalize_kernel(const double* __restrict__ acc,
                                float* __restrict__ out) {
  if (threadIdx.x == 0 && blockIdx.x == 0) {
    const double n  = acc[4];
    const double vf = 0.5 * acc[2] / n;
    const double pg = acc[3] / n;
    out[0] = (float)(pg + 1.0 * vf);   // VF_COEF = 1.0
  }
}

extern "C" void kernel_launch(void* const* d_in, const int* in_sizes, int n_in,
                              void* d_out, int out_size, void* d_ws, size_t ws_size,
                              hipStream_t stream) {
  const float* logprobs     = (const float*)d_in[0];
  const float* values       = (const float*)d_in[1];
  const float* old_logprobs = (const float*)d_in[2];
  const float* old_values   = (const float*)d_in[3];
  const float* rewards      = (const float*)d_in[4];
  const int*   mask         = (const int*)d_in[5];

  const long total = (long)in_sizes[0];
  const int  B     = (int)(total / T_DIM);

  double* acc = (double*)d_ws;
  hipMemsetAsync(acc, 0, 5 * sizeof(double), stream);

  gae_stats_kernel<<<B, BT, 0, stream>>>(old_values, rewards, acc);
  loss_kernel<<<B, BT, 0, stream>>>(logprobs, values, old_logprobs, old_values,
                                    rewards, mask, acc, total);
  finalize_kernel<<<1, 64, 0, stream>>>(acc, (float*)d_out);
}

// Round 2
// 183.111 us; speedup vs baseline: 1.0874x; 1.0874x over previous
//
#include <hip/hip_runtime.h>

// PPO model loss: GAE (reverse affine scan) + whitening stats + clipped losses.
// Inputs (fp32, B=1024 x T=4096): logprobs, values, old_logprobs, old_values,
// rewards, mask(int32). Output: scalar fp32 loss.
//
// R1: BT=1024 threads/row, CH=4 -> perfectly coalesced float4 loads (lane i
// reads base+16*i), short 4-step serial chain, 16 waves/block.
//
// ws layout (doubles): [0]=sum(adv) [1]=sum(adv^2) [2]=vf_sum [3]=pg_sum [4]=n

static constexpr int T_DIM = 4096;
static constexpr int BT    = 1024;         // threads per block (one row/block)
static constexpr int CH    = T_DIM / BT;   // 4 elements per thread
static constexpr int NW    = BT / 64;      // 16 waves per block

#define CDEC 0.95f          // gamma * lam
#define CLIPR 0.2f
#define CLIPV 0.2f

__device__ __forceinline__ double wave_sum_d(double v) {
#pragma unroll
  for (int d = 32; d > 0; d >>= 1) v += __shfl_down(v, d);
  return v;
}

// Shared scan helper: given per-thread affine (L, M) (chunk suffix scan value
// and decay c^CH), return the carry flowing INTO this thread (the already-
// composed suffix of all later threads in the block/row).
__device__ __forceinline__ float block_suffix_carry(float L, float M,
                                                    int lane, int wave,
                                                    float* wL, float* wM) {
  float sL = L, sM = M;
#pragma unroll
  for (int d = 1; d < 64; d <<= 1) {
    float oL = __shfl_down(sL, d);
    float oM = __shfl_down(sM, d);
    if (lane + d < 64) { sL += sM * oL; sM *= oM; }
  }
  if (lane == 0) { wL[wave] = sL; wM[wave] = sM; }
  __syncthreads();
  float Sw = 0.f;
  for (int w = NW - 1; w > wave; --w) Sw = wL[w] + wM[w] * Sw;
  float nL = __shfl_down(sL, 1);
  float nM = __shfl_down(sM, 1);
  if (lane == 63) { nL = 0.f; nM = 1.f; }
  return nL + nM * Sw;
}

// ---------------- Kernel 1: GAE scan + whitening stats (single pass) --------
__global__ __launch_bounds__(BT) void gae_stats_kernel(
    const float* __restrict__ old_values,
    const float* __restrict__ rewards,
    double* __restrict__ acc) {
  const int row  = blockIdx.x;
  const int tid  = threadIdx.x;
  const int lane = tid & 63;
  const int wave = tid >> 6;
  const float c  = CDEC;
  const long base = (long)row * T_DIM + tid * CH;

  // per-chunk power sums: Qc = sum_{i=1..CH} c^i, Q2 = sum c^{2i}, M = c^CH
  float Qc = 0.f, Q2 = 0.f, M;
  {
    float pw = 1.f;
#pragma unroll
    for (int i = 0; i < CH; ++i) { pw *= c; Qc += pw; Q2 += pw * pw; }
    M = pw;
  }

  const float4 rv = *(const float4*)(rewards + base);
  const float4 vv = *(const float4*)(old_values + base);
  float nv = (tid == BT - 1) ? 0.f : old_values[base + CH];

  // chunk pass, high t -> low t; closed-form stats vs carry
  float L = 0.f, P = 0.f, P2 = 0.f, cross = 0.f, pw = 1.f;
  float d;
  d = rv.w + nv - vv.w; L = d + c * L; pw *= c; P += L; P2 += L * L; cross += L * pw; nv = vv.w;
  d = rv.z + nv - vv.z; L = d + c * L; pw *= c; P += L; P2 += L * L; cross += L * pw; nv = vv.z;
  d = rv.y + nv - vv.y; L = d + c * L; pw *= c; P += L; P2 += L * L; cross += L * pw; nv = vv.y;
  d = rv.x + nv - vv.x; L = d + c * L; pw *= c; P += L; P2 += L * L; cross += L * pw;

  __shared__ float wL[NW], wM[NW];
  const float carry = block_suffix_carry(L, M, lane, wave, wL, wM);

  const float s1 = P + Qc * carry;
  const float s2 = P2 + 2.f * carry * cross + Q2 * carry * carry;

  __shared__ double red[2][NW];
  double r1 = wave_sum_d((double)s1);
  double r2 = wave_sum_d((double)s2);
  if (lane == 0) { red[0][wave] = r1; red[1][wave] = r2; }
  __syncthreads();
  if (tid == 0) {
    double t1 = 0.0, t2 = 0.0;
#pragma unroll
    for (int w = 0; w < NW; ++w) { t1 += red[0][w]; t2 += red[1][w]; }
    atomicAdd(&acc[0], t1);
    atomicAdd(&acc[1], t2);
  }
}

// ---------------- Kernel 2: regenerate adv + losses ------------------------
__global__ __launch_bounds__(BT) void loss_kernel(
    const float* __restrict__ logprobs,
    const float* __restrict__ values,
    const float* __restrict__ old_logprobs,
    const float* __restrict__ old_values,
    const float* __restrict__ rewards,
    const int*   __restrict__ mask,
    double* __restrict__ acc,
    long Ntot) {
  const int row  = blockIdx.x;
  const int tid  = threadIdx.x;
  const int lane = tid & 63;
  const int wave = tid >> 6;
  const float c  = CDEC;
  const long base = (long)row * T_DIM + tid * CH;

  // whitening constants from kernel-1 stats
  const double S1 = acc[0], S2 = acc[1];
  const double mean_d = S1 / (double)Ntot;
  const double var_d  = (S2 - S1 * S1 / (double)Ntot) / (double)(Ntot - 1);
  const float meanf   = (float)mean_d;
  const float invstdf = (float)(1.0 / sqrt(var_d + 1e-8));

  float M;
  {
    float pw = 1.f;
#pragma unroll
    for (int i = 0; i < CH; ++i) pw *= c;
    M = pw;
  }

  const float4 rv = *(const float4*)(rewards + base);
  const float4 vv = *(const float4*)(old_values + base);
  const float4 va = *(const float4*)(values + base);
  const float4 lp = *(const float4*)(logprobs + base);
  const float4 ol = *(const float4*)(old_logprobs + base);
  const int4  mk  = *(const int4*)(mask + base);
  const float nv0 = (tid == BT - 1) ? 0.f : old_values[base + CH];

  // chunk affine (L, M)
  float L = 0.f;
  {
    float nv = nv0, d;
    d = rv.w + nv - vv.w; L = d + c * L; nv = vv.w;
    d = rv.z + nv - vv.z; L = d + c * L; nv = vv.z;
    d = rv.y + nv - vv.y; L = d + c * L; nv = vv.y;
    d = rv.x + nv - vv.x; L = d + c * L;
  }

  __shared__ float wL[NW], wM[NW];
  const float carry = block_suffix_carry(L, M, lane, wave, wL, wM);

  // regenerate adv, compute losses (high t -> low t)
  float A = carry;
  float vf_s = 0.f, pg_s = 0.f, n_s = 0.f;
  {
    float nv = nv0;
#define STEP(RC, VC, AC, LC, OC, MC)                                           \
    {                                                                          \
      const float dd = RC + nv - VC;                                           \
      A = dd + c * A;                                                          \
      const float mf = (float)MC;                                              \
      const float ret = A + VC;                                                \
      const float vc2 = fminf(fmaxf(AC, VC - CLIPV), VC + CLIPV);              \
      const float d1 = AC - ret, d2 = vc2 - ret;                               \
      vf_s += fmaxf(d1 * d1, d2 * d2) * mf;                                    \
      const float lr = (LC - OC) * mf;                                         \
      const float ratio = expf(lr);                                            \
      const float a = (A - meanf) * invstdf;                                   \
      const float p1 = -a * ratio;                                             \
      const float p2 = -a * fminf(fmaxf(ratio, 1.f - CLIPR), 1.f + CLIPR);     \
      pg_s += fmaxf(p1, p2) * mf;                                              \
      n_s += mf;                                                               \
      nv = VC;                                                                 \
    }
    STEP(rv.w, vv.w, va.w, lp.w, ol.w, mk.w)
    STEP(rv.z, vv.z, va.z, lp.z, ol.z, mk.z)
    STEP(rv.y, vv.y, va.y, lp.y, ol.y, mk.y)
    STEP(rv.x, vv.x, va.x, lp.x, ol.x, mk.x)
#undef STEP
  }

  __shared__ double red[3][NW];
  double rv0 = wave_sum_d((double)vf_s);
  double rv1 = wave_sum_d((double)pg_s);
  double rv2 = wave_sum_d((double)n_s);
  if (lane == 0) { red[0][wave] = rv0; red[1][wave] = rv1; red[2][wave] = rv2; }
  __syncthreads();
  if (tid == 0) {
    double t0 = 0.0, t1 = 0.0, t2 = 0.0;
#pragma unroll
    for (int w = 0; w < NW; ++w) { t0 += red[0][w]; t1 += red[1][w]; t2 += red[2][w]; }
    atomicAdd(&acc[2], t0);
    atomicAdd(&acc[3], t1);
    atomicAdd(&acc[4], t2);
  }
}

// ---------------- Kernel 3: finalize ---------------------------------------
__global__ void finalize_kernel(const double* __restrict__ acc,
                                float* __restrict__ out) {
  if (threadIdx.x == 0 && blockIdx.x == 0) {
    const double n  = acc[4];
    const double vf = 0.5 * acc[2] / n;
    const double pg = acc[3] / n;
    out[0] = (float)(pg + 1.0 * vf);   // VF_COEF = 1.0
  }
}

extern "C" void kernel_launch(void* const* d_in, const int* in_sizes, int n_in,
                              void* d_out, int out_size, void* d_ws, size_t ws_size,
                              hipStream_t stream) {
  const float* logprobs     = (const float*)d_in[0];
  const float* values       = (const float*)d_in[1];
  const float* old_logprobs = (const float*)d_in[2];
  const float* old_values   = (const float*)d_in[3];
  const float* rewards      = (const float*)d_in[4];
  const int*   mask         = (const int*)d_in[5];

  const long total = (long)in_sizes[0];
  const int  B     = (int)(total / T_DIM);

  double* acc = (double*)d_ws;
  hipMemsetAsync(acc, 0, 5 * sizeof(double), stream);

  gae_stats_kernel<<<B, BT, 0, stream>>>(old_values, rewards, acc);
  loss_kernel<<<B, BT, 0, stream>>>(logprobs, values, old_logprobs, old_values,
                                    rewards, mask, acc, total);
  finalize_kernel<<<1, 64, 0, stream>>>(acc, (float*)d_out);
}